// Round 11
// baseline (628.880 us; speedup 1.0000x reference)
//
#include <hip/hip_runtime.h>

#define HID 32
#define MIN_WEIGHT -100000.0f

// ---------------------------------------------------------------------------
// async global->LDS, 16B per lane, wave-uniform LDS base (+lane*16 implicit)
__device__ __forceinline__ void gld16(const float* g, float* l) {
    __builtin_amdgcn_global_load_lds(
        (const __attribute__((address_space(1))) unsigned int*)g,
        (__attribute__((address_space(3))) unsigned int*)l, 16, 0, 0);
}

// ---------------------------------------------------------------------------
// STREAMING node kernel over GLOBAL rows (no n_map gather!).
//   o0[g] = relu(emb[g] @ W) @ P0   (and o1[g] = ... @ P1 if TWO)
// Block = 256 thr / 4 waves, TILE = 64 consecutive rows.
//   stage  : global_load_lds, fully sequential 16-64KB per block; source
//            chunk XOR-swizzled by (row&7) so later strided LDS reads are
//            conflict-light (both-sides involution, LDS stays linear).
//   layer 1: lane = row, wave = K-quarter. Per 4-K step: ONE ds_read_b128
//            (lane's own row) + W[j][k] via s_load (j,k,wave all uniform)
//            feeds 128 FMAs -> FMA-instruction-bound (128:1 FMA:LDS).
//   partials: acc[32] -> LDS (REUSING the rows buffer, barrier-guarded),
//            reduce 4 K-quarters + relu -> g, then proj from g (L1-hot P).
template <int ROW, bool TWO>
__global__ __launch_bounds__(256) void snode(
    const float* __restrict__ emb, const float* __restrict__ W,
    const float* __restrict__ P0, const float* __restrict__ P1,
    float* __restrict__ o0, float* __restrict__ o1, int N) {
    constexpr int TILE = 64;
    constexpr int CPR = ROW / 4;    // 16B chunks per row
    constexpr int RPI = 64 / CPR;   // rows per staging instruction
    constexpr int NI = TILE / RPI;  // staging instructions per block
    constexpr int IPW = NI / 4;     // staging instructions per wave
    constexpr int PARTF = 4 * 64 * 36;            // partials floats
    constexpr int NEEDF = PARTF + 64 * 36;        // partials + g
    constexpr int LDSF = (TILE * ROW > NEEDF) ? TILE * ROW : NEEDF;

    __shared__ float lds[LDSF];

    const int tid = threadIdx.x;
    const int w = tid >> 6;
    const int lane = tid & 63;
    const int base = blockIdx.x * TILE;

    // ---- stage: sequential rows, source-swizzled chunks --------------------
    {
        int sub, c;
        if (RPI == 1) { sub = 0; c = lane; }
        else if (RPI == 2) { sub = lane >> 5; c = lane & 31; }
        else { sub = lane >> 4; c = lane & 15; }  // RPI == 4
#pragma unroll
        for (int ii = 0; ii < IPW; ++ii) {
            const int i = w * IPW + ii;
            const int r = i * RPI + sub;
            int gr = base + r;
            if (gr >= N) gr = N - 1;
            const float* src = emb + (size_t)gr * ROW + ((c ^ (r & 7)) << 2);
            gld16(src, &lds[i * RPI * ROW]);
        }
    }
    asm volatile("s_waitcnt vmcnt(0)" ::: "memory");
    __syncthreads();

    // ---- layer 1: lane = row, wave = K-quarter; W via s_load ---------------
    const int r = lane;
    float acc[HID];
#pragma unroll
    for (int k = 0; k < HID; ++k) acc[k] = 0.f;
    {
        const int kb = w * (ROW / 4);  // wave-uniform K base
#pragma unroll
        for (int q4 = 0; q4 < ROW / 16; ++q4) {
            const int qc = (kb >> 2) + q4;  // logical 16B chunk
            float4 rv = *(const float4*)&lds[r * ROW + ((qc ^ (r & 7)) << 2)];
#pragma unroll
            for (int jj = 0; jj < 4; ++jj) {
                const float rvj = ((const float*)&rv)[jj];
                const float* wr = W + (size_t)(kb + q4 * 4 + jj) * HID;  // uniform
#pragma unroll
                for (int k = 0; k < HID; ++k) acc[k] = fmaf(rvj, wr[k], acc[k]);
            }
        }
    }
    __syncthreads();  // all waves done READING rows; buffer may be reused

    // ---- partials -> LDS (reuse rows buffer) -------------------------------
    float* part = lds;  // [4][64][36]
#pragma unroll
    for (int k4 = 0; k4 < HID; k4 += 4) {
        float4 v = {acc[k4], acc[k4 + 1], acc[k4 + 2], acc[k4 + 3]};
        *(float4*)&part[(w * 64 + r) * 36 + k4] = v;
    }
    __syncthreads();

    // ---- reduce K-quarters + relu -> g -------------------------------------
    float* g = lds + PARTF;  // [64][36]
    {
        const int rr = tid >> 2;
        const int c0 = (tid & 3) * 8;
        float4 s0 = {0.f, 0.f, 0.f, 0.f}, s1 = {0.f, 0.f, 0.f, 0.f};
#pragma unroll
        for (int q = 0; q < 4; ++q) {
            float4 a = *(const float4*)&part[(q * 64 + rr) * 36 + c0];
            float4 b = *(const float4*)&part[(q * 64 + rr) * 36 + c0 + 4];
            s0.x += a.x; s0.y += a.y; s0.z += a.z; s0.w += a.w;
            s1.x += b.x; s1.y += b.y; s1.z += b.z; s1.w += b.w;
        }
        float4 r0 = {fmaxf(s0.x, 0.f), fmaxf(s0.y, 0.f), fmaxf(s0.z, 0.f), fmaxf(s0.w, 0.f)};
        float4 r1 = {fmaxf(s1.x, 0.f), fmaxf(s1.y, 0.f), fmaxf(s1.z, 0.f), fmaxf(s1.w, 0.f)};
        *(float4*)&g[rr * 36 + c0] = r0;
        *(float4*)&g[rr * 36 + c0 + 4] = r1;
    }
    __syncthreads();

    // ---- projections: g (LDS broadcast) x P (L1-hot 32B/lane) --------------
    {
        const int rr = tid >> 2;  // row 0..63
        const int cq = tid & 3;   // cols cq*8 .. cq*8+7
        float p0[8] = {0.f, 0.f, 0.f, 0.f, 0.f, 0.f, 0.f, 0.f};
        float p1[8] = {0.f, 0.f, 0.f, 0.f, 0.f, 0.f, 0.f, 0.f};
#pragma unroll
        for (int j0 = 0; j0 < HID; j0 += 4) {
            float4 g4 = *(const float4*)&g[rr * 36 + j0];
#pragma unroll
            for (int jj = 0; jj < 4; ++jj) {
                const float gv = ((const float*)&g4)[jj];
                float4 pa = *(const float4*)&P0[(size_t)(j0 + jj) * HID + cq * 8];
                float4 pb = *(const float4*)&P0[(size_t)(j0 + jj) * HID + cq * 8 + 4];
                p0[0] = fmaf(gv, pa.x, p0[0]); p0[1] = fmaf(gv, pa.y, p0[1]);
                p0[2] = fmaf(gv, pa.z, p0[2]); p0[3] = fmaf(gv, pa.w, p0[3]);
                p0[4] = fmaf(gv, pb.x, p0[4]); p0[5] = fmaf(gv, pb.y, p0[5]);
                p0[6] = fmaf(gv, pb.z, p0[6]); p0[7] = fmaf(gv, pb.w, p0[7]);
                if (TWO) {
                    float4 qa = *(const float4*)&P1[(size_t)(j0 + jj) * HID + cq * 8];
                    float4 qb = *(const float4*)&P1[(size_t)(j0 + jj) * HID + cq * 8 + 4];
                    p1[0] = fmaf(gv, qa.x, p1[0]); p1[1] = fmaf(gv, qa.y, p1[1]);
                    p1[2] = fmaf(gv, qa.z, p1[2]); p1[3] = fmaf(gv, qa.w, p1[3]);
                    p1[4] = fmaf(gv, qb.x, p1[4]); p1[5] = fmaf(gv, qb.y, p1[5]);
                    p1[6] = fmaf(gv, qb.z, p1[6]); p1[7] = fmaf(gv, qb.w, p1[7]);
                }
            }
        }
        const int node = base + rr;
        if (node < N) {
            float4 v0 = {p0[0], p0[1], p0[2], p0[3]};
            float4 v1 = {p0[4], p0[5], p0[6], p0[7]};
            *(float4*)&o0[(size_t)node * HID + cq * 8] = v0;
            *(float4*)&o0[(size_t)node * HID + cq * 8 + 4] = v1;
            if (TWO) {
                float4 u0 = {p1[0], p1[1], p1[2], p1[3]};
                float4 u1 = {p1[4], p1[5], p1[6], p1[7]};
                *(float4*)&o1[(size_t)node * HID + cq * 8] = u0;
                *(float4*)&o1[(size_t)node * HID + cq * 8 + 4] = u1;
            }
        }
    }
}

// ---------------------------------------------------------------------------
// Per-edge: tables are GLOBAL-indexed; n_map/offset_node hops are L2-hot.
// att = relu(SA[n_map[src]] + DB[n_map[dst]] + T2[n_map[offset[batch]]] + be1)
//       @ We2 + be2.  att -> own slab, MIN_WEIGHT -> other slab.
__global__ __launch_bounds__(256) void edge_kernel(
    const int* __restrict__ hop_idx, int n_e, const int* __restrict__ src,
    const int* __restrict__ dst, const int* __restrict__ e_batch,
    const int* __restrict__ n_map, const int* __restrict__ offset_node,
    const float* __restrict__ SA, const float* __restrict__ DB,
    const float* __restrict__ T2, const float* __restrict__ be1,
    const float* __restrict__ We2, const float* __restrict__ be2,
    float* __restrict__ out_att, float* __restrict__ out_min) {
    int i = blockIdx.x * blockDim.x + threadIdx.x;
    if (i >= n_e) return;
    int e = hop_idx[i];
    int gs = n_map[src[e]];
    int gd = n_map[dst[e]];
    int gt = n_map[offset_node[e_batch[e]]];
    const float* sv = SA + (size_t)gs * HID;
    const float* dv = DB + (size_t)gd * HID;
    const float* tv = T2 + (size_t)gt * HID;
    float att = be2[0];
#pragma unroll
    for (int k = 0; k < HID; k += 4) {
        float4 s4 = *(const float4*)(sv + k);
        float4 d4 = *(const float4*)(dv + k);
        float4 t4 = *(const float4*)(tv + k);
        float h;
        h = fmaxf(s4.x + d4.x + t4.x + be1[k + 0], 0.f); att = fmaf(h, We2[k + 0], att);
        h = fmaxf(s4.y + d4.y + t4.y + be1[k + 1], 0.f); att = fmaf(h, We2[k + 1], att);
        h = fmaxf(s4.z + d4.z + t4.z + be1[k + 2], 0.f); att = fmaf(h, We2[k + 2], att);
        h = fmaxf(s4.w + d4.w + t4.w + be1[k + 3], 0.f); att = fmaf(h, We2[k + 3], att);
    }
    out_att[e] = att;
    out_min[e] = MIN_WEIGHT;
}

// ---------------------------------------------------------------------------
extern "C" void kernel_launch(void* const* d_in, const int* in_sizes, int n_in,
                              void* d_out, int out_size, void* d_ws, size_t ws_size,
                              hipStream_t stream) {
    const float* emb0 = (const float*)d_in[0];
    const float* emb1 = (const float*)d_in[1];
    const float* emb2 = (const float*)d_in[2];
    const int* n_map = (const int*)d_in[3];
    const int* src = (const int*)d_in[4];
    const int* dst = (const int*)d_in[5];
    const int* e_batch = (const int*)d_in[6];
    const int* offset_node = (const int*)d_in[7];
    const int* one_hop = (const int*)d_in[8];
    const int* two_hop = (const int*)d_in[9];
    const float* W0 = (const float*)d_in[10];
    const float* W1 = (const float*)d_in[11];
    const float* W2 = (const float*)d_in[12];
    const float* We1 = (const float*)d_in[13];
    const float* be1 = (const float*)d_in[14];
    const float* We2 = (const float*)d_in[15];
    const float* be2 = (const float*)d_in[16];

    const int N_GLOBAL = in_sizes[0] / 128;  // rows in each all_emb table
    const int E = in_sizes[4];
    const int H1 = in_sizes[8];  // one-hop edge count
    const int H2 = in_sizes[9];  // two-hop edge count

    float* out = (float*)d_out;

    const float* A = We1;             // rows 0..31   (multiplies s)
    const float* B = We1 + 32 * HID;  // rows 32..63  (multiplies d)
    const float* T = We1 + 64 * HID;  // rows 64..95  (multiplies t)

    // workspace: GLOBAL-indexed tables  a0g | a1g | b1g | b2g | t2g
    float* a0g = (float*)d_ws;
    float* a1g = a0g + (size_t)N_GLOBAL * HID;
    float* b1g = a1g + (size_t)N_GLOBAL * HID;
    float* b2g = b1g + (size_t)N_GLOBAL * HID;
    float* t2g = b2g + (size_t)N_GLOBAL * HID;

    const int gblk = (N_GLOBAL + 63) / 64;
    // a1g = relu(emb1@W1)@A ; b1g = relu(emb1@W1)@B   (streaming, no gather)
    snode<256, true><<<gblk, 256, 0, stream>>>(emb1, W1, A, B, a1g, b1g, N_GLOBAL);
    // a0g = relu(emb0@W0)@A
    snode<128, false><<<gblk, 256, 0, stream>>>(emb0, W0, A, nullptr, a0g, nullptr, N_GLOBAL);
    // b2g = relu(emb2@W2)@B ; t2g = relu(emb2@W2)@T
    snode<64, true><<<gblk, 256, 0, stream>>>(emb2, W2, B, T, b2g, t2g, N_GLOBAL);

    // one-hop edges: att -> slab 1, MIN -> slab 0 (src via W1@A, dst via W2@B)
    edge_kernel<<<(H1 + 255) / 256, 256, 0, stream>>>(
        one_hop, H1, src, dst, e_batch, n_map, offset_node, a1g, b2g, t2g,
        be1, We2, be2, out + (size_t)E, out);
    // two-hop edges: att -> slab 0, MIN -> slab 1 (src via W0@A, dst via W1@B)
    edge_kernel<<<(H2 + 255) / 256, 256, 0, stream>>>(
        two_hop, H2, src, dst, e_batch, n_map, offset_node, a0g, b1g, t2g,
        be1, We2, be2, out, out + (size_t)E);
}